// Round 1
// 406.119 us; speedup vs baseline: 2.1851x; 2.1851x over previous
//
#include <hip/hip_runtime.h>

// ---------------- constants ----------------
#define BATCH 4
#define NPIL 12000
#define NPTS 32
#define NCH 9
#define NXg 432
#define NYg 496
#define OHh 248
#define OWw 216
#define HWp (OHh*OWw)          // 53568
#define CAN_STRIDE ((size_t)NYg*NXg*64)      // ushort elems (bf16 canvas)
#define X1_STRIDE  ((size_t)OHh*OWw*64)      // ushort elems (bf16 x1)
#define X2_STRIDE  ((size_t)OHh*OWw*128)     // float elems

typedef __bf16 bf16x8 __attribute__((ext_vector_type(8)));
typedef float  f32x4  __attribute__((ext_vector_type(4)));

__device__ __forceinline__ bf16x8 as_bf16x8(uint4 u) {
    union { uint4 u; bf16x8 b; } c; c.u = u; return c.b;
}

__device__ __forceinline__ float b2f(unsigned int u) {
    union { unsigned int i; float f; } x; x.i = (u & 0xffffu) << 16; return x.f;
}
__device__ __forceinline__ unsigned short f2b(float f) {
    union { float f; unsigned int i; } x; x.f = f;
    unsigned int r = x.i + 0x7fffu + ((x.i >> 16) & 1u);   // RNE
    return (unsigned short)(r >> 16);
}
__device__ __forceinline__ float ldin(const void* p, int i, int isbf) {
    return isbf ? b2f(((const unsigned short*)p)[i]) : ((const float*)p)[i];
}

__global__ void sentinel_kernel(float* out, float val) {
    if (threadIdx.x == 0) out[0] = val;
}

// ---------------- per-tensor dtype detector (robustness; all fp32 in practice) ----------------
__device__ __forceinline__ int plaus16(unsigned short h) {
    if ((h & 0x7fffu) == 0) return 1;
    unsigned e = (h >> 7) & 0xffu;
    return (e >= 106 && e <= 132) ? 1 : 0;
}

__global__ __launch_bounds__(1024) void detect_all(
    const void* q0,  const void* q1,  const void* q2,  const void* q3,
    const void* q4,  const void* q5,  const void* q6,  const void* q7,
    const void* q8,  const void* q9,  const void* q10, const void* q11,
    const void* q12, const void* q13, const void* q14, const void* q15,
    const void* q16, const void* q17, const void* q18, const void* q19,
    const void* q20, const void* q21, int* __restrict__ flags)
{
    __shared__ int votes[22];
    const void* ptrs[22] = {q0,q1,q2,q3,q4,q5,q6,q7,q8,q9,q10,q11,
                            q12,q13,q14,q15,q16,q17,q18,q19,q20,q21};
    const int Ks[22]   = {64,64,32,32,32,32,64,32,32,32,32,64,64,64,64,64,64,3,64,7,64,2};
    const int didx[22] = {0,3,4,5,6,7,8,9,10,11,12,13,14,15,16,17,18,19,20,21,22,23};
    const int tid = threadIdx.x;
    if (tid < 22) votes[tid] = 0;
    __syncthreads();
    int off = 0;
    #pragma unroll 1
    for (int t = 0; t < 22; ++t) {
        const int K = Ks[t];
        if (tid >= off && tid < off + K) {
            unsigned w = ((const unsigned*)ptrs[t])[tid - off];
            if (plaus16((unsigned short)w) && plaus16((unsigned short)(w >> 16)))
                atomicAdd(&votes[t], 1);
        }
        off += K;
    }
    __syncthreads();
    if (tid < 22) {
        int isbf;
        if (tid == 17 || tid == 19 || tid == 21) {
            int pv = votes[17] + votes[19] + votes[21];
            isbf = (pv * 4 >= 3 * 12);
        } else {
            isbf = (votes[tid] * 4 >= 3 * Ks[tid]);
        }
        flags[didx[tid]] = isbf;
    }
}

// ---------------- weight transpose: OIHW -> bf16 [ky*3+kx][oc][ic] ----------------
__global__ __launch_bounds__(256) void prep_weights(
    const void* __restrict__ w1, const void* __restrict__ w2,
    unsigned short* __restrict__ wt1, unsigned short* __restrict__ wt2,
    const int* __restrict__ flags)
{
    const int f1 = flags[8], f2 = flags[13];
    int i = blockIdx.x * 256 + threadIdx.x;
    if (i < 64*64*9) {
        int kx = i % 3; int t = i / 3; int ky = t % 3; t /= 3; int ic = t % 64; int oc = t / 64;
        wt1[((size_t)(ky*3 + kx)*64 + oc)*64 + ic] = f2b(ldin(w1, i, f1));
    }
    if (i < 128*64*9) {
        int kx = i % 3; int t = i / 3; int ky = t % 3; t /= 3; int ic = t % 64; int oc = t / 64;
        wt2[((size_t)(ky*3 + kx)*128 + oc)*64 + ic] = f2b(ldin(w2, i, f2));
    }
}

// ---------------- PFN + scatter, canvas NHWC bf16 [NY,NX,64] ----------------
__global__ __launch_bounds__(256) void pfn_scatter(
    const void* __restrict__ pillars, const int* __restrict__ coords,
    const void* __restrict__ pfn_w,
    const void* __restrict__ g, const void* __restrict__ bb,
    const void* __restrict__ m, const void* __restrict__ v,
    const int* __restrict__ flags, int b0,
    unsigned short* __restrict__ canvas)
{
    __shared__ float lds[4][NPTS*NCH];
    const int wslot = threadIdx.x >> 6;
    const int lane  = threadIdx.x & 63;
    const int p = blockIdx.x * 4 + wslot;
    const int b = b0 + blockIdx.y;
    canvas += (size_t)blockIdx.y * CAN_STRIDE;
    const size_t pg = (size_t)b * NPIL + p;

    if (flags[0]) {
        const unsigned short* src = (const unsigned short*)pillars + pg * (NPTS*NCH);
        for (int idx = lane; idx < NPTS*NCH; idx += 64) lds[wslot][idx] = b2f(src[idx]);
    } else {
        const float4* src = (const float4*)((const float*)pillars + pg * (NPTS*NCH));
        for (int idx = lane; idx < (NPTS*NCH)/4; idx += 64)
            *(float4*)&lds[wslot][idx*4] = src[idx];
    }
    float w[NCH];
    const int fW = flags[3];
    #pragma unroll
    for (int c = 0; c < NCH; ++c) w[c] = ldin(pfn_w, lane*NCH + c, fW);
    float s = ldin(g, lane, flags[4]) / sqrtf(ldin(v, lane, flags[7]) + 1e-5f);
    float t = ldin(bb, lane, flags[5]) - ldin(m, lane, flags[6]) * s;
    __syncthreads();

    float mx = 0.0f;
    #pragma unroll 4
    for (int n = 0; n < NPTS; ++n) {
        const float* r = &lds[wslot][n*NCH];
        float acc = r[0] * w[0];
        #pragma unroll
        for (int c = 1; c < NCH; ++c) acc = fmaf(r[c], w[c], acc);
        mx = fmaxf(mx, fmaxf(fmaf(acc, s, t), 0.0f));
    }
    const int cx = coords[pg*2], cy = coords[pg*2 + 1];
    if (cx + cy != 0 && cx >= 0 && cx < NXg && cy >= 0 && cy < NYg)
        canvas[((size_t)cy*NXg + cx)*64 + lane] = f2b(mx);
}

// ---------------- conv1 (MFMA): canvas bf16 -> x1 bf16 [248,216,64], stride 2 ----------------
// Block = 16 px x 16 oy x 64 oc. 4 waves; wave w owns oy_loc 4w..4w+3 (m-tiles), 16 px = m,
// 4 n-tiles of 16 oc. K = 9 taps x (2 ksteps of 32 ic).
// lin: per-ky halo [16 rows][33 cols][8 slots x 16B], XOR-swizzled slot = sl ^ ((c>>1)&7)
//   (stride-2 column access -> key on c>>1 keeps A-reads 2-way/free and writes conflict-free).
// lw: single-buffered per-(ky,kx) [64 oc][8 slots], slot ^= (oc&7).
// LDS = 67,584 + 8,192 = 75,776 B -> 2 blocks/CU.
__global__ __launch_bounds__(256, 2) void conv1_mfma(
    const unsigned short* __restrict__ canvas,
    const unsigned short* __restrict__ wt,     // bf16 [9][64 oc][64 ic]
    const void* __restrict__ g, const void* __restrict__ bb,
    const void* __restrict__ m, const void* __restrict__ v,
    const int* __restrict__ flags,
    unsigned short* __restrict__ x1)
{
    __shared__ uint4 lin[16*33*8];   // 67,584 B
    __shared__ uint4 lw[64*8];       //  8,192 B
    const int tid = threadIdx.x;
    const int w = tid >> 6, l = tid & 63;
    const int lr = l & 15, lg = l >> 4;
    const int px0 = blockIdx.x * 16, oy0 = blockIdx.y * 16;
    canvas += (size_t)blockIdx.z * CAN_STRIDE;
    x1     += (size_t)blockIdx.z * X1_STRIDE;

    f32x4 acc[4][4];
    #pragma unroll
    for (int t = 0; t < 4; ++t)
        #pragma unroll
        for (int n = 0; n < 4; ++n) acc[t][n] = (f32x4){0.f,0.f,0.f,0.f};

    #pragma unroll 1
    for (int ky = 0; ky < 3; ++ky) {
        __syncthreads();                       // drain readers of lin/lw
        for (int q = tid; q < 16*33*8; q += 256) {
            int sl = q & 7, t2 = q >> 3, c = t2 % 33, r = t2 / 33;
            int iy = 2*oy0 + ky - 1 + 2*r, gx = 2*px0 - 1 + c;
            uint4 d = make_uint4(0u,0u,0u,0u);
            if ((unsigned)iy < (unsigned)NYg && (unsigned)gx < (unsigned)NXg)
                d = *(const uint4*)&canvas[((size_t)iy*NXg + gx)*64 + sl*8];
            lin[(r*33 + c)*8 + (sl ^ ((c >> 1) & 7))] = d;
        }
        #pragma unroll 1
        for (int kx = 0; kx < 3; ++kx) {
            if (kx) __syncthreads();           // drain lw readers
            for (int q = tid; q < 64*8; q += 256) {
                int sl = q & 7, oc = q >> 3;
                lw[oc*8 + (sl ^ (oc & 7))] =
                    *(const uint4*)&wt[((size_t)(ky*3 + kx)*64 + oc)*64 + sl*8];
            }
            __syncthreads();
            const int c = 2*lr + kx;           // A: m = lane&15 -> px, col in halo
            const int key = (c >> 1) & 7;
            bf16x8 af[4][2];
            #pragma unroll
            for (int t = 0; t < 4; ++t) {
                const int base = ((4*w + t)*33 + c)*8;
                af[t][0] = as_bf16x8(lin[base + (lg ^ key)]);
                af[t][1] = as_bf16x8(lin[base + ((4 + lg) ^ key)]);
            }
            #pragma unroll
            for (int n = 0; n < 4; ++n) {
                const int oc = n*16 + lr;      // B: n = lane&15 -> oc
                const bf16x8 b0 = as_bf16x8(lw[oc*8 + (lg ^ (oc & 7))]);
                const bf16x8 b1 = as_bf16x8(lw[oc*8 + ((4 + lg) ^ (oc & 7))]);
                #pragma unroll
                for (int t = 0; t < 4; ++t) {
                    acc[t][n] = __builtin_amdgcn_mfma_f32_16x16x32_bf16(af[t][0], b0, acc[t][n], 0, 0, 0);
                    acc[t][n] = __builtin_amdgcn_mfma_f32_16x16x32_bf16(af[t][1], b1, acc[t][n], 0, 0, 0);
                }
            }
        }
    }
    float s[4], tt[4];
    #pragma unroll
    for (int n = 0; n < 4; ++n) {
        const int oc = n*16 + lr;
        s[n]  = ldin(g, oc, flags[9]) / sqrtf(ldin(v, oc, flags[12]) + 1e-5f);
        tt[n] = ldin(bb, oc, flags[10]) - ldin(m, oc, flags[11]) * s[n];
    }
    // D: col = lane&15 = oc, row = (lane>>4)*4 + reg = px
    #pragma unroll
    for (int t = 0; t < 4; ++t) {
        const int oy = oy0 + 4*w + t;
        if (oy >= OHh) continue;
        #pragma unroll
        for (int r = 0; r < 4; ++r) {
            const int px = px0 + lg*4 + r;
            if (px >= OWw) continue;
            unsigned short* orow = &x1[((size_t)oy*OWw + px)*64 + lr];
            #pragma unroll
            for (int n = 0; n < 4; ++n)
                orow[n*16] = f2b(fmaxf(fmaf(acc[t][n][r], s[n], tt[n]), 0.f));
        }
    }
}

// ---------------- conv2 (MFMA): x1 bf16 -> x2 fp32 [248,216,128], stride 1 ----------------
// Block = 16 px x 16 oy x 128 oc. lin staged once [18][18][8 slots]; lw double-buffered
// per-tap [128 oc][8 slots] with register prefetch (loads issued before the tap's MFMAs,
// ds_write after -> HBM/L2 latency hides under MFMA). LDS = 41,472 + 32,768 = 74,240 B
// -> 2 blocks/CU. One barrier per tap.
__global__ __launch_bounds__(256, 2) void conv2_mfma(
    const unsigned short* __restrict__ x1,
    const unsigned short* __restrict__ wt,     // bf16 [9][128 oc][64 ic]
    const void* __restrict__ g, const void* __restrict__ bb,
    const void* __restrict__ m, const void* __restrict__ v,
    const int* __restrict__ flags,
    float* __restrict__ out)
{
    __shared__ uint4 lin[18*18*8];   // 41,472 B
    __shared__ uint4 lw[2][128*8];   // 32,768 B
    const int tid = threadIdx.x;
    const int w = tid >> 6, l = tid & 63;
    const int lr = l & 15, lg = l >> 4;
    const int px0 = blockIdx.x * 16, oy0 = blockIdx.y * 16;
    x1  += (size_t)blockIdx.z * X1_STRIDE;
    out += (size_t)blockIdx.z * X2_STRIDE;

    for (int q = tid; q < 18*18*8; q += 256) {
        int sl = q & 7, t2 = q >> 3, c = t2 % 18, r = t2 / 18;
        int iy = oy0 - 1 + r, gx = px0 - 1 + c;
        uint4 d = make_uint4(0u,0u,0u,0u);
        if ((unsigned)iy < (unsigned)OHh && (unsigned)gx < (unsigned)OWw)
            d = *(const uint4*)&x1[((size_t)iy*OWw + gx)*64 + sl*8];
        lin[(r*18 + c)*8 + (sl ^ (c & 7))] = d;
    }
    uint4 wreg[4];
    #pragma unroll
    for (int i = 0; i < 4; ++i) {
        const int q = tid + i*256;
        wreg[i] = *(const uint4*)&wt[((size_t)(q >> 3))*64 + (q & 7)*8];
    }
    #pragma unroll
    for (int i = 0; i < 4; ++i) {
        const int q = tid + i*256, sl = q & 7, oc = q >> 3;
        lw[0][oc*8 + (sl ^ (oc & 7))] = wreg[i];
    }
    __syncthreads();

    f32x4 acc[4][8];
    #pragma unroll
    for (int t = 0; t < 4; ++t)
        #pragma unroll
        for (int n = 0; n < 8; ++n) acc[t][n] = (f32x4){0.f,0.f,0.f,0.f};

    #pragma unroll 1
    for (int tap = 0; tap < 9; ++tap) {
        const int ky = tap / 3, kx = tap - 3*ky;
        const int cur = tap & 1;
        if (tap < 8) {                          // prefetch next tap's weights to regs
            #pragma unroll
            for (int i = 0; i < 4; ++i) {
                const int q = tid + i*256;
                wreg[i] = *(const uint4*)&wt[((size_t)(tap+1)*128 + (q >> 3))*64 + (q & 7)*8];
            }
        }
        const int c = lr + kx;
        const int key = c & 7;
        bf16x8 af[4][2];
        #pragma unroll
        for (int t = 0; t < 4; ++t) {
            const int base = ((4*w + t + ky)*18 + c)*8;
            af[t][0] = as_bf16x8(lin[base + (lg ^ key)]);
            af[t][1] = as_bf16x8(lin[base + ((4 + lg) ^ key)]);
        }
        #pragma unroll
        for (int n = 0; n < 8; ++n) {
            const int oc = n*16 + lr;
            const bf16x8 b0 = as_bf16x8(lw[cur][oc*8 + (lg ^ (oc & 7))]);
            const bf16x8 b1 = as_bf16x8(lw[cur][oc*8 + ((4 + lg) ^ (oc & 7))]);
            #pragma unroll
            for (int t = 0; t < 4; ++t) {
                acc[t][n] = __builtin_amdgcn_mfma_f32_16x16x32_bf16(af[t][0], b0, acc[t][n], 0, 0, 0);
                acc[t][n] = __builtin_amdgcn_mfma_f32_16x16x32_bf16(af[t][1], b1, acc[t][n], 0, 0, 0);
            }
        }
        if (tap < 8) {                          // write-late into the other buffer
            #pragma unroll
            for (int i = 0; i < 4; ++i) {
                const int q = tid + i*256, sl = q & 7, oc = q >> 3;
                lw[cur ^ 1][oc*8 + (sl ^ (oc & 7))] = wreg[i];
            }
        }
        __syncthreads();
    }

    float s[8], tt[8];
    #pragma unroll
    for (int n = 0; n < 8; ++n) {
        const int oc = n*16 + lr;
        s[n]  = ldin(g, oc, flags[14]) / sqrtf(ldin(v, oc, flags[17]) + 1e-5f);
        tt[n] = ldin(bb, oc, flags[15]) - ldin(m, oc, flags[16]) * s[n];
    }
    #pragma unroll
    for (int t = 0; t < 4; ++t) {
        const int oy = oy0 + 4*w + t;
        if (oy >= OHh) continue;
        #pragma unroll
        for (int r = 0; r < 4; ++r) {
            const int px = px0 + lg*4 + r;
            if (px >= OWw) continue;
            float* orow = &out[((size_t)oy*OWw + px)*128 + lr];
            #pragma unroll
            for (int n = 0; n < 8; ++n)
                orow[n*16] = fmaxf(fmaf(acc[t][n][r], s[n], tt[n]), 0.f);
        }
    }
}

// ---------------- detection heads (1x1 convs), fp32 out ----------------
__global__ __launch_bounds__(256) void heads_kernel(
    const float* __restrict__ x2,
    const void* __restrict__ cls_w, const void* __restrict__ cls_b,
    const void* __restrict__ reg_w, const void* __restrict__ reg_b,
    const void* __restrict__ dir_w, const void* __restrict__ dir_b,
    const int* __restrict__ flags, int nb, int b0,
    float* __restrict__ out)
{
    __shared__ float lw[24*128];
    __shared__ float lb[24];
    const int tid = threadIdx.x;
    for (int idx = tid; idx < 6*128;  idx += 256) lw[idx]          = ldin(cls_w, idx, flags[18]);
    for (int idx = tid; idx < 14*128; idx += 256) lw[6*128 + idx]  = ldin(reg_w, idx, flags[20]);
    for (int idx = tid; idx < 4*128;  idx += 256) lw[20*128 + idx] = ldin(dir_w, idx, flags[22]);
    if (tid < 6)       lb[tid] = ldin(cls_b, tid, flags[19]);
    else if (tid < 20) lb[tid] = ldin(reg_b, tid - 6, flags[21]);
    else if (tid < 24) lb[tid] = ldin(dir_b, tid - 20, flags[23]);
    __syncthreads();

    const int gpix = blockIdx.x * 256 + tid;
    int b, pix;
    const float* xrow;
    if (nb > 1) {
        if (gpix >= nb*HWp) return;
        b = gpix / HWp; pix = gpix - b*HWp;
        xrow = x2 + (size_t)b * X2_STRIDE + (size_t)pix * 128;
    } else {
        if (gpix >= HWp) return;
        b = b0; pix = gpix;
        xrow = x2 + (size_t)pix * 128;
    }

    float acc[24];
    #pragma unroll
    for (int o = 0; o < 24; ++o) acc[o] = lb[o];
    #pragma unroll 2
    for (int kb = 0; kb < 128; kb += 16) {
        float xv[16];
        #pragma unroll
        for (int j = 0; j < 4; ++j) {
            float4 v4 = *(const float4*)(xrow + kb + 4*j);
            xv[4*j] = v4.x; xv[4*j+1] = v4.y; xv[4*j+2] = v4.z; xv[4*j+3] = v4.w;
        }
        #pragma unroll
        for (int k = 0; k < 16; ++k)
            #pragma unroll
            for (int o = 0; o < 24; ++o)
                acc[o] = fmaf(xv[k], lw[o*128 + kb + k], acc[o]);
    }
    const size_t reg_base = (size_t)BATCH*6*HWp;
    const size_t dir_base = reg_base + (size_t)BATCH*14*HWp;
    #pragma unroll
    for (int o = 0; o < 6; ++o)
        out[((size_t)b*6 + o)*HWp + pix] = acc[o];
    #pragma unroll
    for (int o = 0; o < 14; ++o)
        out[reg_base + ((size_t)b*14 + o)*HWp + pix] = acc[6 + o];
    #pragma unroll
    for (int o = 0; o < 4; ++o)
        out[dir_base + ((size_t)b*4 + o)*HWp + pix] = acc[20 + o];
}

extern "C" void kernel_launch(void* const* d_in, const int* in_sizes, int n_in,
                              void* d_out, int out_size, void* d_ws, size_t ws_size,
                              hipStream_t stream) {
    static const int EXPECT[24] = {13824000,96000,48000,576,64,64,64,64,36864,
                                   64,64,64,64,73728,128,128,128,128,768,6,1792,14,512,4};
    const void* din[24];
    {
        bool used[24] = {false};
        int perm[24];
        bool ok = (n_in >= 24);
        if (ok) {
            for (int j = 0; j < 24 && ok; ++j) {
                perm[j] = -1;
                for (int i = 0; i < 24; ++i)
                    if (!used[i] && in_sizes[i] == EXPECT[j]) { perm[j] = i; used[i] = true; break; }
                if (perm[j] < 0) ok = false;
            }
        }
        for (int j = 0; j < 24; ++j) din[j] = d_in[ok ? perm[j] : j];
        if (!ok) {
            sentinel_kernel<<<1, 64, 0, stream>>>((float*)d_out, 13000.0f + n_in);
            return;
        }
    }
    const int* coords = (const int*)din[1];
    float* out = (float*)d_out;

    // layout: flags 256B | wt1 bf16 73,728B | wt2 bf16 147,456B |
    //         x1 bf16 (nb x 6,856,704) | canvas bf16 (nb x 27,426,816; x2 fp32 aliases)
    const size_t X1B  = (size_t)HWp*64*2;          // 6,856,704
    const size_t CANB = (size_t)NYg*NXg*64*2;      // 27,426,816 (== x2 fp32 bytes)
    const size_t BASE = 256 + 73728 + 147456;      // 221,440
    const size_t NEED1 = BASE + X1B + CANB;        // 34,504,960
    const size_t NEED4 = BASE + 4*(X1B + CANB);    // 137,355,520
    if (ws_size < NEED1) {
        sentinel_kernel<<<1, 64, 0, stream>>>(out, 10000.0f + (float)(ws_size >> 20));
        return;
    }
    const int nb = (ws_size >= NEED4) ? 4 : 1;
    char* ws = (char*)d_ws;
    int* flags = (int*)ws;
    unsigned short* wt1 = (unsigned short*)(ws + 256);
    unsigned short* wt2 = (unsigned short*)(ws + 256 + 73728);
    unsigned short* x1  = (unsigned short*)(ws + BASE);
    unsigned short* canvas = (unsigned short*)(ws + BASE + (size_t)nb*X1B);
    float* x2 = (float*)canvas;                    // aliases canvas (dead after conv1)

    detect_all<<<1, 1024, 0, stream>>>(
        din[0], din[3], din[4], din[5], din[6], din[7],
        din[8], din[9], din[10], din[11], din[12],
        din[13], din[14], din[15], din[16], din[17],
        din[18], din[19], din[20], din[21], din[22], din[23], flags);
    prep_weights<<<288, 256, 0, stream>>>(din[8], din[13], wt1, wt2, flags);

    if (nb == 4) {
        hipMemsetAsync(canvas, 0, 4*CANB, stream);
        pfn_scatter<<<dim3(NPIL/4, 4), 256, 0, stream>>>(
            din[0], coords, din[3], din[4], din[5], din[6], din[7], flags, 0, canvas);
        conv1_mfma<<<dim3(14, 16, 4), 256, 0, stream>>>(
            canvas, wt1, din[9], din[10], din[11], din[12], flags, x1);
        conv2_mfma<<<dim3(14, 16, 4), 256, 0, stream>>>(
            x1, wt2, din[14], din[15], din[16], din[17], flags, x2);
        heads_kernel<<<(4*HWp)/256, 256, 0, stream>>>(
            x2, din[18], din[19], din[20], din[21], din[22], din[23], flags, 4, 0, out);
    } else {
        for (int b = 0; b < BATCH; ++b) {
            hipMemsetAsync(canvas, 0, CANB, stream);
            pfn_scatter<<<dim3(NPIL/4, 1), 256, 0, stream>>>(
                din[0], coords, din[3], din[4], din[5], din[6], din[7], flags, b, canvas);
            conv1_mfma<<<dim3(14, 16, 1), 256, 0, stream>>>(
                canvas, wt1, din[9], din[10], din[11], din[12], flags, x1);
            conv2_mfma<<<dim3(14, 16, 1), 256, 0, stream>>>(
                x1, wt2, din[14], din[15], din[16], din[17], flags, x2);
            heads_kernel<<<(HWp + 255)/256, 256, 0, stream>>>(
                x2, din[18], din[19], din[20], din[21], din[22], din[23], flags, 1, b, out);
        }
    }
}

// Round 2
// 386.082 us; speedup vs baseline: 2.2985x; 1.0519x over previous
//
#include <hip/hip_runtime.h>

// ---------------- constants ----------------
#define BATCH 4
#define NPIL 12000
#define NPTS 32
#define NCH 9
#define NXg 432
#define NYg 496
#define OHh 248
#define OWw 216
#define HWp (OHh*OWw)          // 53568
#define CAN_STRIDE ((size_t)NYg*NXg*64)      // ushort elems (bf16 canvas)
#define X1_STRIDE  ((size_t)OHh*OWw*64)      // ushort elems (bf16 x1)

typedef __bf16 bf16x8 __attribute__((ext_vector_type(8)));
typedef float  f32x4  __attribute__((ext_vector_type(4)));

__device__ __forceinline__ bf16x8 as_bf16x8(uint4 u) {
    union { uint4 u; bf16x8 b; } c; c.u = u; return c.b;
}

__device__ __forceinline__ float b2f(unsigned int u) {
    union { unsigned int i; float f; } x; x.i = (u & 0xffffu) << 16; return x.f;
}
__device__ __forceinline__ unsigned short f2b(float f) {
    union { float f; unsigned int i; } x; x.f = f;
    unsigned int r = x.i + 0x7fffu + ((x.i >> 16) & 1u);   // RNE
    return (unsigned short)(r >> 16);
}
__device__ __forceinline__ float ldin(const void* p, int i, int isbf) {
    return isbf ? b2f(((const unsigned short*)p)[i]) : ((const float*)p)[i];
}

__global__ void sentinel_kernel(float* out, float val) {
    if (threadIdx.x == 0) out[0] = val;
}

// ---------------- per-tensor dtype detector (robustness; all fp32 in practice) ----------------
__device__ __forceinline__ int plaus16(unsigned short h) {
    if ((h & 0x7fffu) == 0) return 1;
    unsigned e = (h >> 7) & 0xffu;
    return (e >= 106 && e <= 132) ? 1 : 0;
}

__global__ __launch_bounds__(1024) void detect_all(
    const void* q0,  const void* q1,  const void* q2,  const void* q3,
    const void* q4,  const void* q5,  const void* q6,  const void* q7,
    const void* q8,  const void* q9,  const void* q10, const void* q11,
    const void* q12, const void* q13, const void* q14, const void* q15,
    const void* q16, const void* q17, const void* q18, const void* q19,
    const void* q20, const void* q21, int* __restrict__ flags)
{
    __shared__ int votes[22];
    const void* ptrs[22] = {q0,q1,q2,q3,q4,q5,q6,q7,q8,q9,q10,q11,
                            q12,q13,q14,q15,q16,q17,q18,q19,q20,q21};
    const int Ks[22]   = {64,64,32,32,32,32,64,32,32,32,32,64,64,64,64,64,64,3,64,7,64,2};
    const int didx[22] = {0,3,4,5,6,7,8,9,10,11,12,13,14,15,16,17,18,19,20,21,22,23};
    const int tid = threadIdx.x;
    if (tid < 22) votes[tid] = 0;
    __syncthreads();
    int off = 0;
    #pragma unroll 1
    for (int t = 0; t < 22; ++t) {
        const int K = Ks[t];
        if (tid >= off && tid < off + K) {
            unsigned w = ((const unsigned*)ptrs[t])[tid - off];
            if (plaus16((unsigned short)w) && plaus16((unsigned short)(w >> 16)))
                atomicAdd(&votes[t], 1);
        }
        off += K;
    }
    __syncthreads();
    if (tid < 22) {
        int isbf;
        if (tid == 17 || tid == 19 || tid == 21) {
            int pv = votes[17] + votes[19] + votes[21];
            isbf = (pv * 4 >= 3 * 12);
        } else {
            isbf = (votes[tid] * 4 >= 3 * Ks[tid]);
        }
        flags[didx[tid]] = isbf;
    }
}

// ---------------- weight prep ----------------
// wt1/wt2: OIHW -> bf16 [tap][oc][ic].  Head weights: concat(cls6,reg14,dir4) padded to 32 oc,
// split into hi/lo bf16 pairs laid out [o(32)][ic(128)] so B-fragments are direct 16B loads.
__global__ __launch_bounds__(256) void prep_weights(
    const void* __restrict__ w1, const void* __restrict__ w2,
    const void* __restrict__ cls_w, const void* __restrict__ reg_w, const void* __restrict__ dir_w,
    unsigned short* __restrict__ wt1, unsigned short* __restrict__ wt2,
    unsigned short* __restrict__ whh, unsigned short* __restrict__ whl,
    const int* __restrict__ flags)
{
    const int f1 = flags[8], f2 = flags[13];
    int i = blockIdx.x * 256 + threadIdx.x;
    if (i < 64*64*9) {
        int kx = i % 3; int t = i / 3; int ky = t % 3; t /= 3; int ic = t % 64; int oc = t / 64;
        wt1[((size_t)(ky*3 + kx)*64 + oc)*64 + ic] = f2b(ldin(w1, i, f1));
    }
    if (i < 128*64*9) {
        int kx = i % 3; int t = i / 3; int ky = t % 3; t /= 3; int ic = t % 64; int oc = t / 64;
        wt2[((size_t)(ky*3 + kx)*128 + oc)*64 + ic] = f2b(ldin(w2, i, f2));
    }
    if (i < 32*128) {
        int ic = i & 127, o = i >> 7;
        float wv = 0.f;
        if (o < 6)       wv = ldin(cls_w, o*128 + ic, flags[18]);
        else if (o < 20) wv = ldin(reg_w, (o-6)*128 + ic, flags[20]);
        else if (o < 24) wv = ldin(dir_w, (o-20)*128 + ic, flags[22]);
        unsigned short hi = f2b(wv);
        whh[i] = hi;
        whl[i] = f2b(wv - b2f(hi));
    }
}

// ---------------- PFN + scatter, canvas NHWC bf16 [NY,NX,64] ----------------
__global__ __launch_bounds__(256) void pfn_scatter(
    const void* __restrict__ pillars, const int* __restrict__ coords,
    const void* __restrict__ pfn_w,
    const void* __restrict__ g, const void* __restrict__ bb,
    const void* __restrict__ m, const void* __restrict__ v,
    const int* __restrict__ flags, int b0,
    unsigned short* __restrict__ canvas)
{
    __shared__ float lds[4][NPTS*NCH];
    const int wslot = threadIdx.x >> 6;
    const int lane  = threadIdx.x & 63;
    const int p = blockIdx.x * 4 + wslot;
    const int b = b0 + blockIdx.y;
    canvas += (size_t)blockIdx.y * CAN_STRIDE;
    const size_t pg = (size_t)b * NPIL + p;

    if (flags[0]) {
        const unsigned short* src = (const unsigned short*)pillars + pg * (NPTS*NCH);
        for (int idx = lane; idx < NPTS*NCH; idx += 64) lds[wslot][idx] = b2f(src[idx]);
    } else {
        const float4* src = (const float4*)((const float*)pillars + pg * (NPTS*NCH));
        for (int idx = lane; idx < (NPTS*NCH)/4; idx += 64)
            *(float4*)&lds[wslot][idx*4] = src[idx];
    }
    float w[NCH];
    const int fW = flags[3];
    #pragma unroll
    for (int c = 0; c < NCH; ++c) w[c] = ldin(pfn_w, lane*NCH + c, fW);
    float s = ldin(g, lane, flags[4]) / sqrtf(ldin(v, lane, flags[7]) + 1e-5f);
    float t = ldin(bb, lane, flags[5]) - ldin(m, lane, flags[6]) * s;
    __syncthreads();

    float mx = 0.0f;
    #pragma unroll 4
    for (int n = 0; n < NPTS; ++n) {
        const float* r = &lds[wslot][n*NCH];
        float acc = r[0] * w[0];
        #pragma unroll
        for (int c = 1; c < NCH; ++c) acc = fmaf(r[c], w[c], acc);
        mx = fmaxf(mx, fmaxf(fmaf(acc, s, t), 0.0f));
    }
    const int cx = coords[pg*2], cy = coords[pg*2 + 1];
    if (cx + cy != 0 && cx >= 0 && cx < NXg && cy >= 0 && cy < NYg)
        canvas[((size_t)cy*NXg + cx)*64 + lane] = f2b(mx);
}

// ---------------- conv1 (MFMA): canvas bf16 -> x1 bf16 [248,216,64], stride 2 ----------------
// B-fragments loaded directly from global wt1 (73KB, L2-resident) -> no lw LDS, no weight
// barriers: 2 barriers per ky only. LDS = 67,584 B -> 2 blocks/CU.
__global__ __launch_bounds__(256, 2) void conv1_mfma(
    const unsigned short* __restrict__ canvas,
    const unsigned short* __restrict__ wt,     // bf16 [9][64 oc][64 ic]
    const void* __restrict__ g, const void* __restrict__ bb,
    const void* __restrict__ m, const void* __restrict__ v,
    const int* __restrict__ flags,
    unsigned short* __restrict__ x1)
{
    __shared__ __align__(16) uint4 lin[16*33*8];   // 67,584 B
    const int tid = threadIdx.x;
    const int w = tid >> 6, l = tid & 63;
    const int lr = l & 15, lg = l >> 4;
    const int px0 = blockIdx.x * 16, oy0 = blockIdx.y * 16;
    canvas += (size_t)blockIdx.z * CAN_STRIDE;
    x1     += (size_t)blockIdx.z * X1_STRIDE;

    f32x4 acc[4][4];
    #pragma unroll
    for (int t = 0; t < 4; ++t)
        #pragma unroll
        for (int n = 0; n < 4; ++n) acc[t][n] = (f32x4){0.f,0.f,0.f,0.f};

    #pragma unroll 1
    for (int ky = 0; ky < 3; ++ky) {
        __syncthreads();                       // drain readers of lin
        for (int q = tid; q < 16*33*8; q += 256) {
            int sl = q & 7, t2 = q >> 3, c = t2 % 33, r = t2 / 33;
            int iy = 2*oy0 + ky - 1 + 2*r, gx = 2*px0 - 1 + c;
            uint4 d = make_uint4(0u,0u,0u,0u);
            if ((unsigned)iy < (unsigned)NYg && (unsigned)gx < (unsigned)NXg)
                d = *(const uint4*)&canvas[((size_t)iy*NXg + gx)*64 + sl*8];
            lin[(r*33 + c)*8 + (sl ^ ((c >> 1) & 7))] = d;
        }
        __syncthreads();
        #pragma unroll 1
        for (int kx = 0; kx < 3; ++kx) {
            const int tap = ky*3 + kx;
            uint4 wb[4][2];
            #pragma unroll
            for (int n = 0; n < 4; ++n)
                #pragma unroll
                for (int ks = 0; ks < 2; ++ks)
                    wb[n][ks] = *(const uint4*)&wt[((size_t)(tap*64 + n*16 + lr))*64 + ks*32 + lg*8];
            const int c = 2*lr + kx;
            const int key = (c >> 1) & 7;
            #pragma unroll
            for (int t = 0; t < 4; ++t) {
                const int base = ((4*w + t)*33 + c)*8;
                bf16x8 a0 = as_bf16x8(lin[base + (lg ^ key)]);
                bf16x8 a1 = as_bf16x8(lin[base + ((4 + lg) ^ key)]);
                #pragma unroll
                for (int n = 0; n < 4; ++n) {
                    acc[t][n] = __builtin_amdgcn_mfma_f32_16x16x32_bf16(a0, as_bf16x8(wb[n][0]), acc[t][n], 0, 0, 0);
                    acc[t][n] = __builtin_amdgcn_mfma_f32_16x16x32_bf16(a1, as_bf16x8(wb[n][1]), acc[t][n], 0, 0, 0);
                }
            }
        }
    }
    float s[4], tt[4];
    #pragma unroll
    for (int n = 0; n < 4; ++n) {
        const int oc = n*16 + lr;
        s[n]  = ldin(g, oc, flags[9]) / sqrtf(ldin(v, oc, flags[12]) + 1e-5f);
        tt[n] = ldin(bb, oc, flags[10]) - ldin(m, oc, flags[11]) * s[n];
    }
    // D: col = lane&15 = oc, row = (lane>>4)*4 + reg = px
    #pragma unroll
    for (int t = 0; t < 4; ++t) {
        const int oy = oy0 + 4*w + t;
        if (oy >= OHh) continue;
        #pragma unroll
        for (int r = 0; r < 4; ++r) {
            const int px = px0 + lg*4 + r;
            if (px >= OWw) continue;
            unsigned short* orow = &x1[((size_t)oy*OWw + px)*64 + lr];
            #pragma unroll
            for (int n = 0; n < 4; ++n)
                orow[n*16] = f2b(fmaxf(fmaf(acc[t][n][r], s[n], tt[n]), 0.f));
        }
    }
}

// ---------------- conv2 (MFMA) + fused heads ----------------
// Main loop identical to the verified r1 kernel (lw double-buffer, 1 barrier/tap).
// Epilogue: x2 tile (256 px x 128 ch) never goes to HBM. It is written to LDS (overlaying
// lin/lw) as bf16 hi, heads computed with MFMA vs hi/lo-split weights, then the lo residual
// pass: out = P_hi*W_hi + P_hi*W_lo + P_lo*W_hi  (error ~2^-17 -> absmax unchanged).
// P layout: [px 256][slot' 16][8 ch] with slot' = (ch>>3) ^ (px&15) -> conflict-free A-reads.
__global__ __launch_bounds__(256, 2) void conv2_mfma(
    const unsigned short* __restrict__ x1,
    const unsigned short* __restrict__ wt,     // bf16 [9][128 oc][64 ic]
    const unsigned short* __restrict__ whh,    // bf16 [32 o][128 ic] head W hi
    const unsigned short* __restrict__ whl,    // bf16 [32 o][128 ic] head W lo
    const void* __restrict__ g, const void* __restrict__ bb,
    const void* __restrict__ m, const void* __restrict__ v,
    const void* __restrict__ cls_b, const void* __restrict__ reg_b, const void* __restrict__ dir_b,
    const int* __restrict__ flags, int b0,
    float* __restrict__ out)
{
    __shared__ __align__(16) char smem[74240];     // lin 41,472 | lw 32,768 ; P overlays first 65,536
    uint4* lin = (uint4*)smem;
    uint4 (*lw)[128*8] = (uint4 (*)[128*8])(smem + 41472);
    unsigned short* P = (unsigned short*)smem;

    const int tid = threadIdx.x;
    const int w = tid >> 6, l = tid & 63;
    const int lr = l & 15, lg = l >> 4;
    const int px0 = blockIdx.x * 16, oy0 = blockIdx.y * 16;
    const int b = b0 + blockIdx.z;
    x1 += (size_t)blockIdx.z * X1_STRIDE;

    for (int q = tid; q < 18*18*8; q += 256) {
        int sl = q & 7, t2 = q >> 3, c = t2 % 18, r = t2 / 18;
        int iy = oy0 - 1 + r, gx = px0 - 1 + c;
        uint4 d = make_uint4(0u,0u,0u,0u);
        if ((unsigned)iy < (unsigned)OHh && (unsigned)gx < (unsigned)OWw)
            d = *(const uint4*)&x1[((size_t)iy*OWw + gx)*64 + sl*8];
        lin[(r*18 + c)*8 + (sl ^ (c & 7))] = d;
    }
    uint4 wreg[4];
    #pragma unroll
    for (int i = 0; i < 4; ++i) {
        const int q = tid + i*256;
        wreg[i] = *(const uint4*)&wt[((size_t)(q >> 3))*64 + (q & 7)*8];
    }
    #pragma unroll
    for (int i = 0; i < 4; ++i) {
        const int q = tid + i*256, sl = q & 7, oc = q >> 3;
        lw[0][oc*8 + (sl ^ (oc & 7))] = wreg[i];
    }
    __syncthreads();

    f32x4 acc[4][8];
    #pragma unroll
    for (int t = 0; t < 4; ++t)
        #pragma unroll
        for (int n = 0; n < 8; ++n) acc[t][n] = (f32x4){0.f,0.f,0.f,0.f};

    #pragma unroll 1
    for (int tap = 0; tap < 9; ++tap) {
        const int ky = tap / 3, kx = tap - 3*ky;
        const int cur = tap & 1;
        if (tap < 8) {                          // prefetch next tap's weights to regs
            #pragma unroll
            for (int i = 0; i < 4; ++i) {
                const int q = tid + i*256;
                wreg[i] = *(const uint4*)&wt[((size_t)(tap+1)*128 + (q >> 3))*64 + (q & 7)*8];
            }
        }
        const int c = lr + kx;
        const int key = c & 7;
        bf16x8 af[4][2];
        #pragma unroll
        for (int t = 0; t < 4; ++t) {
            const int base = ((4*w + t + ky)*18 + c)*8;
            af[t][0] = as_bf16x8(lin[base + (lg ^ key)]);
            af[t][1] = as_bf16x8(lin[base + ((4 + lg) ^ key)]);
        }
        #pragma unroll
        for (int n = 0; n < 8; ++n) {
            const int oc = n*16 + lr;
            const bf16x8 b0 = as_bf16x8(lw[cur][oc*8 + (lg ^ (oc & 7))]);
            const bf16x8 b1 = as_bf16x8(lw[cur][oc*8 + ((4 + lg) ^ (oc & 7))]);
            #pragma unroll
            for (int t = 0; t < 4; ++t) {
                acc[t][n] = __builtin_amdgcn_mfma_f32_16x16x32_bf16(af[t][0], b0, acc[t][n], 0, 0, 0);
                acc[t][n] = __builtin_amdgcn_mfma_f32_16x16x32_bf16(af[t][1], b1, acc[t][n], 0, 0, 0);
            }
        }
        if (tap < 8) {
            #pragma unroll
            for (int i = 0; i < 4; ++i) {
                const int q = tid + i*256, sl = q & 7, oc = q >> 3;
                lw[cur ^ 1][oc*8 + (sl ^ (oc & 7))] = wreg[i];
            }
        }
        __syncthreads();
    }

    float s[8], tt[8];
    #pragma unroll
    for (int n = 0; n < 8; ++n) {
        const int oc = n*16 + lr;
        s[n]  = ldin(g, oc, flags[14]) / sqrtf(ldin(v, oc, flags[17]) + 1e-5f);
        tt[n] = ldin(bb, oc, flags[15]) - ldin(m, oc, flags[16]) * s[n];
    }

    // ---- fused heads ----
    // head bias per lane (n-tile 0: o=lr; n-tile 1: o=16+lr, pad>=24 -> 0)
    float bias0, bias1;
    {
        int o = lr;
        bias0 = (o < 6) ? ldin(cls_b, o, flags[19]) : ldin(reg_b, o - 6, flags[21]);
        o = 16 + lr;
        bias1 = (o < 20) ? ldin(reg_b, o - 6, flags[21])
              : (o < 24) ? ldin(dir_b, o - 20, flags[23]) : 0.f;
    }
    // head weight B-fragments (L2-hot, 16 KB total)
    uint4 wh[2][4], wl[2][4];
    #pragma unroll
    for (int n = 0; n < 2; ++n)
        #pragma unroll
        for (int ks = 0; ks < 4; ++ks) {
            const int ei = (n*16 + lr)*128 + ks*32 + lg*8;
            wh[n][ks] = *(const uint4*)&whh[ei];
            wl[n][ks] = *(const uint4*)&whl[ei];
        }

    __syncthreads();            // all waves done reading lin/lw before P overlay
    // fill P with hi; convert acc -> lo residual in place
    #pragma unroll
    for (int t = 0; t < 4; ++t) {
        const int pb = ((4*w + t)*16 + lg*4) * 128;
        #pragma unroll
        for (int n = 0; n < 8; ++n) {
            const int kk = 2*n + (lr >> 3), wi = lr & 7;
            #pragma unroll
            for (int r = 0; r < 4; ++r) {
                float val = fmaxf(fmaf(acc[t][n][r], s[n], tt[n]), 0.f);
                unsigned short h = f2b(val);
                P[pb + r*128 + ((kk ^ (lg*4 + r)) << 3) + wi] = h;
                acc[t][n][r] = val - b2f(h);
            }
        }
    }
    __syncthreads();

    f32x4 hacc[4][2];
    #pragma unroll
    for (int t = 0; t < 4; ++t) {
        hacc[t][0] = (f32x4){bias0, bias0, bias0, bias0};
        hacc[t][1] = (f32x4){bias1, bias1, bias1, bias1};
    }
    // pass 1: hi*Whi + hi*Wlo
    #pragma unroll
    for (int t = 0; t < 4; ++t) {
        const int mt = 4*w + t;
        bf16x8 pa[4];
        #pragma unroll
        for (int ks = 0; ks < 4; ++ks)
            pa[ks] = as_bf16x8(((const uint4*)P)[(mt*16 + lr)*16 + ((ks*4 + lg) ^ lr)]);
        #pragma unroll
        for (int n = 0; n < 2; ++n)
            #pragma unroll
            for (int ks = 0; ks < 4; ++ks) {
                hacc[t][n] = __builtin_amdgcn_mfma_f32_16x16x32_bf16(pa[ks], as_bf16x8(wh[n][ks]), hacc[t][n], 0, 0, 0);
                hacc[t][n] = __builtin_amdgcn_mfma_f32_16x16x32_bf16(pa[ks], as_bf16x8(wl[n][ks]), hacc[t][n], 0, 0, 0);
            }
    }
    __syncthreads();
    // fill P with lo
    #pragma unroll
    for (int t = 0; t < 4; ++t) {
        const int pb = ((4*w + t)*16 + lg*4) * 128;
        #pragma unroll
        for (int n = 0; n < 8; ++n) {
            const int kk = 2*n + (lr >> 3), wi = lr & 7;
            #pragma unroll
            for (int r = 0; r < 4; ++r)
                P[pb + r*128 + ((kk ^ (lg*4 + r)) << 3) + wi] = f2b(acc[t][n][r]);
        }
    }
    __syncthreads();
    // pass 2: lo*Whi
    #pragma unroll
    for (int t = 0; t < 4; ++t) {
        const int mt = 4*w + t;
        bf16x8 pa[4];
        #pragma unroll
        for (int ks = 0; ks < 4; ++ks)
            pa[ks] = as_bf16x8(((const uint4*)P)[(mt*16 + lr)*16 + ((ks*4 + lg) ^ lr)]);
        #pragma unroll
        for (int n = 0; n < 2; ++n)
            #pragma unroll
            for (int ks = 0; ks < 4; ++ks)
                hacc[t][n] = __builtin_amdgcn_mfma_f32_16x16x32_bf16(pa[ks], as_bf16x8(wh[n][ks]), hacc[t][n], 0, 0, 0);
    }

    // write heads output: D col = lane&15 = o, rows = px (4 contiguous -> float4)
    const size_t regbase = (size_t)BATCH*6*HWp;
    const size_t dirbase = regbase + (size_t)BATCH*14*HWp;
    const int pxw = px0 + lg*4;
    #pragma unroll
    for (int n = 0; n < 2; ++n) {
        const int o = n*16 + lr;
        float* plane;
        bool valid = (pxw < OWw);
        if (o < 6)       plane = out + ((size_t)b*6 + o)*HWp;
        else if (o < 20) plane = out + regbase + ((size_t)b*14 + (o - 6))*HWp;
        else if (o < 24) plane = out + dirbase + ((size_t)b*4 + (o - 20))*HWp;
        else valid = false;
        if (!valid) continue;
        #pragma unroll
        for (int t = 0; t < 4; ++t) {
            const int oy = oy0 + 4*w + t;
            if (oy < OHh)
                *(float4*)&plane[(size_t)oy*OWw + pxw] = *(float4*)&hacc[t][n];
        }
    }
}

extern "C" void kernel_launch(void* const* d_in, const int* in_sizes, int n_in,
                              void* d_out, int out_size, void* d_ws, size_t ws_size,
                              hipStream_t stream) {
    static const int EXPECT[24] = {13824000,96000,48000,576,64,64,64,64,36864,
                                   64,64,64,64,73728,128,128,128,128,768,6,1792,14,512,4};
    const void* din[24];
    {
        bool used[24] = {false};
        int perm[24];
        bool ok = (n_in >= 24);
        if (ok) {
            for (int j = 0; j < 24 && ok; ++j) {
                perm[j] = -1;
                for (int i = 0; i < 24; ++i)
                    if (!used[i] && in_sizes[i] == EXPECT[j]) { perm[j] = i; used[i] = true; break; }
                if (perm[j] < 0) ok = false;
            }
        }
        for (int j = 0; j < 24; ++j) din[j] = d_in[ok ? perm[j] : j];
        if (!ok) {
            sentinel_kernel<<<1, 64, 0, stream>>>((float*)d_out, 13000.0f + n_in);
            return;
        }
    }
    const int* coords = (const int*)din[1];
    float* out = (float*)d_out;

    // layout: flags 256 | wt1 73,728 | wt2 147,456 | whh 8,192 | whl 8,192 |
    //         x1 bf16 (nb x 6,856,704) | canvas bf16 (nb x 27,426,816)
    const size_t X1B  = (size_t)HWp*64*2;          // 6,856,704
    const size_t CANB = (size_t)NYg*NXg*64*2;      // 27,426,816
    const size_t BASE = 256 + 73728 + 147456 + 8192 + 8192;   // 237,824
    const size_t NEED1 = BASE + X1B + CANB;
    const size_t NEED4 = BASE + 4*(X1B + CANB);
    if (ws_size < NEED1) {
        sentinel_kernel<<<1, 64, 0, stream>>>(out, 10000.0f + (float)(ws_size >> 20));
        return;
    }
    const int nb = (ws_size >= NEED4) ? 4 : 1;
    char* ws = (char*)d_ws;
    int* flags = (int*)ws;
    unsigned short* wt1 = (unsigned short*)(ws + 256);
    unsigned short* wt2 = (unsigned short*)(ws + 256 + 73728);
    unsigned short* whh = (unsigned short*)(ws + 256 + 73728 + 147456);
    unsigned short* whl = (unsigned short*)(ws + 256 + 73728 + 147456 + 8192);
    unsigned short* x1  = (unsigned short*)(ws + BASE);
    unsigned short* canvas = (unsigned short*)(ws + BASE + (size_t)nb*X1B);

    detect_all<<<1, 1024, 0, stream>>>(
        din[0], din[3], din[4], din[5], din[6], din[7],
        din[8], din[9], din[10], din[11], din[12],
        din[13], din[14], din[15], din[16], din[17],
        din[18], din[19], din[20], din[21], din[22], din[23], flags);
    prep_weights<<<288, 256, 0, stream>>>(
        din[8], din[13], din[18], din[20], din[22], wt1, wt2, whh, whl, flags);

    if (nb == 4) {
        hipMemsetAsync(canvas, 0, 4*CANB, stream);
        pfn_scatter<<<dim3(NPIL/4, 4), 256, 0, stream>>>(
            din[0], coords, din[3], din[4], din[5], din[6], din[7], flags, 0, canvas);
        conv1_mfma<<<dim3(14, 16, 4), 256, 0, stream>>>(
            canvas, wt1, din[9], din[10], din[11], din[12], flags, x1);
        conv2_mfma<<<dim3(14, 16, 4), 256, 0, stream>>>(
            x1, wt2, whh, whl, din[14], din[15], din[16], din[17],
            din[19], din[21], din[23], flags, 0, out);
    } else {
        for (int b = 0; b < BATCH; ++b) {
            hipMemsetAsync(canvas, 0, CANB, stream);
            pfn_scatter<<<dim3(NPIL/4, 1), 256, 0, stream>>>(
                din[0], coords, din[3], din[4], din[5], din[6], din[7], flags, b, canvas);
            conv1_mfma<<<dim3(14, 16, 1), 256, 0, stream>>>(
                canvas, wt1, din[9], din[10], din[11], din[12], flags, x1);
            conv2_mfma<<<dim3(14, 16, 1), 256, 0, stream>>>(
                x1, wt2, whh, whl, din[14], din[15], din[16], din[17],
                din[19], din[21], din[23], flags, b, out);
        }
    }
}